// Round 1
// baseline (503.862 us; speedup 1.0000x reference)
//
#include <hip/hip_runtime.h>
#include <math.h>

#define N_ROWS 8192
#define DIM    512
#define NT     (N_ROWS / 128)        // 64 block-tiles per dim
#define NBLK   (NT * (NT + 1) / 2)   // 2080 lower-triangle tiles (2080 % 8 == 0)

typedef __bf16 bf16x8 __attribute__((ext_vector_type(8)));
typedef float  floatx4 __attribute__((ext_vector_type(4)));

__device__ __forceinline__ unsigned short f2bf_rne(float x) {
    union { float f; unsigned u; } v; v.f = x;
    unsigned r = v.u + 0x7FFFu + ((v.u >> 16) & 1u);
    return (unsigned short)(r >> 16);
}

// async global->LDS, 16B per lane. LDS dest must be wave-uniform base + lane*16.
__device__ __forceinline__ void async_cp16(const void* g, void* l) {
    __builtin_amdgcn_global_load_lds(
        (const __attribute__((address_space(1))) unsigned int*)g,
        (__attribute__((address_space(3))) unsigned int*)l,
        16, 0, 0);
}

// Kernel 1: one wave per row. fp32 sq_norm + bf16 convert. (~8 us, unchanged)
__global__ __launch_bounds__(256) void fs_norm_convert(
    const float* __restrict__ F, unsigned short* __restrict__ Fb,
    float* __restrict__ sn) {
    const int wave = threadIdx.x >> 6;
    const int lane = threadIdx.x & 63;
    const int row  = blockIdx.x * 4 + wave;

    const float4* src = reinterpret_cast<const float4*>(F + (size_t)row * DIM) + lane * 2;
    float4 x0 = src[0];
    float4 x1 = src[1];

    float ss = x0.x*x0.x + x0.y*x0.y + x0.z*x0.z + x0.w*x0.w
             + x1.x*x1.x + x1.y*x1.y + x1.z*x1.z + x1.w*x1.w;

    uint4 p;
    p.x = (unsigned)f2bf_rne(x0.x) | ((unsigned)f2bf_rne(x0.y) << 16);
    p.y = (unsigned)f2bf_rne(x0.z) | ((unsigned)f2bf_rne(x0.w) << 16);
    p.z = (unsigned)f2bf_rne(x1.x) | ((unsigned)f2bf_rne(x1.y) << 16);
    p.w = (unsigned)f2bf_rne(x1.z) | ((unsigned)f2bf_rne(x1.w) << 16);
    reinterpret_cast<uint4*>(Fb + (size_t)row * DIM)[lane] = p;

    #pragma unroll
    for (int off = 32; off > 0; off >>= 1) ss += __shfl_down(ss, off);
    if (lane == 0) sn[row] = ss;
}

// Kernel 2: symmetric GEMM. Only lower-triangle 128x128 block tiles are
// launched; each computes C_tile (acc = mfma(a,b)) AND the mirror tile
// (accT = mfma(b,a)) from the same staged LDS data -> staging + LDS reads
// + barriers halve, MFMA and HBM writes unchanged.
// BK=64 (128B LDS rows) + XOR swizzle (colgrp ^ row&7): pre-swizzled global
// source keeps global_load_lds dest linear (rule 21); ds_read applies the
// same swizzle -> 8-way bank conflict becomes 2-way (free).
// Double-buffered: next tile staged before current tile's compute, single
// __syncthreads() (vmcnt(0)+lgkmcnt(0) drain) per K-tile lands after the
// MFMA phase instead of immediately after issue.
__global__ __launch_bounds__(256, 2) void fs_gemm_sym(
    const unsigned short* __restrict__ Fb, const float* __restrict__ sn,
    float* __restrict__ out) {
    __shared__ unsigned short As[2][128 * 64];   // 16 KiB per buf
    __shared__ unsigned short Bs[2][128 * 64];   // total LDS = 64 KiB -> 2 blocks/CU

    const int tid  = threadIdx.x;
    const int lane = tid & 63;
    const int wave = tid >> 6;
    const int wr   = wave >> 1;      // wave row 0..1
    const int wc   = wave & 1;       // wave col 0..1
    const int quad = lane >> 4;      // 0..3
    const int l16  = lane & 15;

    // XCD-aware swizzle (bijective: 2080 = 8*260), then linear->triangle.
    // Consecutive L within an XCD chunk share bi -> A-panel L2 reuse.
    int L = (int)blockIdx.x;
    L = (L & 7) * (NBLK / 8) + (L >> 3);
    int bi = (int)((sqrtf(8.0f * (float)L + 1.0f) - 1.0f) * 0.5f);
    while ((bi + 1) * (bi + 2) / 2 <= L) ++bi;   // fixup fp sqrt
    while (bi * (bi + 1) / 2 > L) --bi;
    const int bj   = L - bi * (bi + 1) / 2;
    const int diag = (bi == bj);

    const int bRow = bi * 128;
    const int bCol = bj * 128;

    floatx4 acc[4][4], accT[4][4];
    #pragma unroll
    for (int i = 0; i < 4; ++i)
        #pragma unroll
        for (int j = 0; j < 4; ++j) {
            acc[i][j]  = floatx4{0.f, 0.f, 0.f, 0.f};
            accT[i][j] = floatx4{0.f, 0.f, 0.f, 0.f};
        }

    // Staging: thread tid covers rows r, r+32, r+64, r+96; col-group c (8 elems).
    // Source col-group is pre-swizzled: csw = c ^ (r&7); rows r+32k share r&7.
    const int r   = tid >> 3;        // 0..31
    const int c   = tid & 7;         // 0..7
    const int csw = c ^ (r & 7);
    const unsigned short* gA = Fb + (size_t)(bRow + r) * DIM + csw * 8;
    const unsigned short* gB = Fb + (size_t)(bCol + r) * DIM + csw * 8;

    // Fragment read col offsets (elements), swizzled. row&7 == l16&7 for all t.
    const int cg0 = ((0 + quad) ^ (l16 & 7)) * 8;   // k-half 0: cols quad*8
    const int cg1 = ((4 + quad) ^ (l16 & 7)) * 8;   // k-half 1: cols 32+quad*8

    #define STAGE(buf, k0) {                                        \
        unsigned short* la = &As[buf][tid * 8];                     \
        unsigned short* lb = &Bs[buf][tid * 8];                     \
        const unsigned short* pa = gA + (k0);                       \
        const unsigned short* pb = gB + (k0);                       \
        async_cp16(pa,            la);                              \
        async_cp16(pa + 32 * DIM, la + 2048);                       \
        async_cp16(pa + 64 * DIM, la + 4096);                       \
        async_cp16(pa + 96 * DIM, la + 6144);                       \
        async_cp16(pb,            lb);                              \
        async_cp16(pb + 32 * DIM, lb + 2048);                       \
        async_cp16(pb + 64 * DIM, lb + 4096);                       \
        async_cp16(pb + 96 * DIM, lb + 6144);                       \
    }

    STAGE(0, 0)
    __syncthreads();   // drain prologue stage

    for (int k = 0; k < DIM / 64; ++k) {
        if (k < DIM / 64 - 1) STAGE((k + 1) & 1, (k + 1) * 64)   // prefetch next
        const unsigned short* Ab = As[k & 1];
        const unsigned short* Bb = Bs[k & 1];
        #pragma unroll
        for (int h = 0; h < 2; ++h) {
            const int cg = h ? cg1 : cg0;
            bf16x8 af[4], bf[4];
            #pragma unroll
            for (int t = 0; t < 4; ++t) {
                af[t] = *reinterpret_cast<const bf16x8*>(
                    Ab + (wr * 64 + t * 16 + l16) * 64 + cg);
                bf[t] = *reinterpret_cast<const bf16x8*>(
                    Bb + (wc * 64 + t * 16 + l16) * 64 + cg);
            }
            if (diag) {
                #pragma unroll
                for (int i = 0; i < 4; ++i)
                    #pragma unroll
                    for (int j = 0; j < 4; ++j)
                        acc[i][j] = __builtin_amdgcn_mfma_f32_16x16x32_bf16(
                            af[i], bf[j], acc[i][j], 0, 0, 0);
            } else {
                #pragma unroll
                for (int i = 0; i < 4; ++i)
                    #pragma unroll
                    for (int j = 0; j < 4; ++j) {
                        acc[i][j]  = __builtin_amdgcn_mfma_f32_16x16x32_bf16(
                            af[i], bf[j], acc[i][j], 0, 0, 0);
                        accT[i][j] = __builtin_amdgcn_mfma_f32_16x16x32_bf16(
                            bf[i], af[j], accT[i][j], 0, 0, 0);
                    }
            }
        }
        __syncthreads();   // drains vmcnt(0): prefetched tile complete, reads done
    }

    // Epilogue. C/D layout: col = lane&15, row = quad*4 + reg.
    // Tile (bi,bj): rows from A side, cols from B side.
    {
        const int row0 = bRow + wr * 64;
        const int col0 = bCol + wc * 64;
        float snc[4];
        #pragma unroll
        for (int j = 0; j < 4; ++j) snc[j] = sn[col0 + j * 16 + l16];

        #pragma unroll
        for (int i = 0; i < 4; ++i) {
            #pragma unroll
            for (int rr = 0; rr < 4; ++rr) {
                const int row = row0 + i * 16 + quad * 4 + rr;
                const float snr = sn[row];
                float* orow = out + (size_t)row * N_ROWS;
                #pragma unroll
                for (int j = 0; j < 4; ++j) {
                    const int col = col0 + j * 16 + l16;
                    float v = snr + snc[j] - 2.0f * acc[i][j][rr];
                    v = fmaxf(v, 0.0f);
                    orow[col] = (row == col) ? 0.0f : -sqrtf(v);
                }
            }
        }
    }

    // Mirror tile (bj,bi): accT[p][q] = mfma(bf[p], af[q]) -> rows from B side,
    // cols from A side, already in coalesced-writable layout. Skip on diagonal.
    if (!diag) {
        const int rowT0 = bCol + wc * 64;
        const int colT0 = bRow + wr * 64;
        float snq[4];
        #pragma unroll
        for (int q = 0; q < 4; ++q) snq[q] = sn[colT0 + q * 16 + l16];

        #pragma unroll
        for (int p = 0; p < 4; ++p) {
            #pragma unroll
            for (int rr = 0; rr < 4; ++rr) {
                const int row = rowT0 + p * 16 + quad * 4 + rr;
                const float snr = sn[row];
                float* orow = out + (size_t)row * N_ROWS;
                #pragma unroll
                for (int q = 0; q < 4; ++q) {
                    const int col = colT0 + q * 16 + l16;
                    float v = snr + snq[q] - 2.0f * accT[p][q][rr];
                    orow[col] = -sqrtf(fmaxf(v, 0.0f));
                }
            }
        }
    }
}

extern "C" void kernel_launch(void* const* d_in, const int* in_sizes, int n_in,
                              void* d_out, int out_size, void* d_ws, size_t ws_size,
                              hipStream_t stream) {
    const float* F = (const float*)d_in[0];
    float* out = (float*)d_out;

    unsigned short* Fb = (unsigned short*)d_ws;                       // 8 MiB bf16 copy
    float* sn = (float*)((char*)d_ws + (size_t)N_ROWS * DIM * 2);     // 32 KiB norms

    fs_norm_convert<<<N_ROWS / 4, 256, 0, stream>>>(F, Fb, sn);

    fs_gemm_sym<<<dim3(NBLK), 256, 0, stream>>>(Fb, sn, out);
}

// Round 2
// 326.561 us; speedup vs baseline: 1.5429x; 1.5429x over previous
//
#include <hip/hip_runtime.h>
#include <math.h>

#define N_ROWS 8192
#define DIM    512
#define NT     (N_ROWS / 128)        // 64 block-tiles per dim
#define NBLK   (NT * (NT + 1) / 2)   // 2080 lower-triangle tiles (2080 % 8 == 0)

typedef __bf16 bf16x8 __attribute__((ext_vector_type(8)));
typedef float  floatx4 __attribute__((ext_vector_type(4)));

__device__ __forceinline__ unsigned short f2bf_rne(float x) {
    union { float f; unsigned u; } v; v.f = x;
    unsigned r = v.u + 0x7FFFu + ((v.u >> 16) & 1u);
    return (unsigned short)(r >> 16);
}

// async global->LDS, 16B per lane. LDS dest must be wave-uniform base + lane*16.
__device__ __forceinline__ void async_cp16(const void* g, void* l) {
    __builtin_amdgcn_global_load_lds(
        (const __attribute__((address_space(1))) unsigned int*)g,
        (__attribute__((address_space(3))) unsigned int*)l,
        16, 0, 0);
}

// Kernel 1: one wave per row. fp32 sq_norm + bf16 convert. (~8 us, unchanged)
__global__ __launch_bounds__(256) void fs_norm_convert(
    const float* __restrict__ F, unsigned short* __restrict__ Fb,
    float* __restrict__ sn) {
    const int wave = threadIdx.x >> 6;
    const int lane = threadIdx.x & 63;
    const int row  = blockIdx.x * 4 + wave;

    const float4* src = reinterpret_cast<const float4*>(F + (size_t)row * DIM) + lane * 2;
    float4 x0 = src[0];
    float4 x1 = src[1];

    float ss = x0.x*x0.x + x0.y*x0.y + x0.z*x0.z + x0.w*x0.w
             + x1.x*x1.x + x1.y*x1.y + x1.z*x1.z + x1.w*x1.w;

    uint4 p;
    p.x = (unsigned)f2bf_rne(x0.x) | ((unsigned)f2bf_rne(x0.y) << 16);
    p.y = (unsigned)f2bf_rne(x0.z) | ((unsigned)f2bf_rne(x0.w) << 16);
    p.z = (unsigned)f2bf_rne(x1.x) | ((unsigned)f2bf_rne(x1.y) << 16);
    p.w = (unsigned)f2bf_rne(x1.z) | ((unsigned)f2bf_rne(x1.w) << 16);
    reinterpret_cast<uint4*>(Fb + (size_t)row * DIM)[lane] = p;

    #pragma unroll
    for (int off = 32; off > 0; off >>= 1) ss += __shfl_down(ss, off);
    if (lane == 0) sn[row] = ss;
}

// Kernel 2: symmetric GEMM, lower-triangle block tiles only.
// Round-2 change vs round-1: NO second accumulator. Each block computes only
// acc = A_tile * B_tile^T (16 MFMAs/phase -> total MFMA work HALVED vs full
// grid). The mirror tile (bj,bi) is the transpose of the finished epilogue
// values (the -sqrt output is symmetric), produced via a per-wave 16 KiB LDS
// transpose that reuses the staging buffers (dead after the K-loop).
// This removes the 128-accum-register pressure that round-1's accT created
// (suspected scratch spill -> 3.7x WRITE_SIZE inflation).
// Kept from round-1 (verified good): BK=64 XOR-swizzled staging (bank
// conflicts = 0), double-buffered global_load_lds prefetch, triangle grid
// with bijective XCD chunking.
__global__ __launch_bounds__(256, 2) void fs_gemm_sym(
    const unsigned short* __restrict__ Fb, const float* __restrict__ sn,
    float* __restrict__ out) {
    // [0]=As buf0, [1]=As buf1, [2]=Bs buf0, [3]=Bs buf1  (64 KiB total).
    // After the K-loop this is reused as 4 x 16 KiB per-wave fp32 transpose
    // scratch.
    __shared__ unsigned short smem[4][128 * 64];

    const int tid  = threadIdx.x;
    const int lane = tid & 63;
    const int wave = tid >> 6;
    const int wr   = wave >> 1;      // wave row 0..1
    const int wc   = wave & 1;       // wave col 0..1
    const int quad = lane >> 4;      // 0..3
    const int l16  = lane & 15;

    // XCD-aware chunking (bijective: 2080 = 8*260), then linear->triangle.
    int L = (int)blockIdx.x;
    L = (L & 7) * (NBLK / 8) + (L >> 3);
    int bi = (int)((sqrtf(8.0f * (float)L + 1.0f) - 1.0f) * 0.5f);
    while ((bi + 1) * (bi + 2) / 2 <= L) ++bi;   // fixup fp sqrt
    while (bi * (bi + 1) / 2 > L) --bi;
    const int bj   = L - bi * (bi + 1) / 2;
    const int diag = (bi == bj);

    const int bRow = bi * 128;
    const int bCol = bj * 128;

    floatx4 acc[4][4];
    #pragma unroll
    for (int i = 0; i < 4; ++i)
        #pragma unroll
        for (int j = 0; j < 4; ++j)
            acc[i][j] = floatx4{0.f, 0.f, 0.f, 0.f};

    // Staging: thread tid covers rows r, r+32, r+64, r+96; col-group c (8 elems).
    // Source col-group is pre-swizzled: csw = c ^ (r&7); rows r+32k share r&7.
    const int r   = tid >> 3;        // 0..31
    const int c   = tid & 7;         // 0..7
    const int csw = c ^ (r & 7);
    const unsigned short* gA = Fb + (size_t)(bRow + r) * DIM + csw * 8;
    const unsigned short* gB = Fb + (size_t)(bCol + r) * DIM + csw * 8;

    // Fragment read col offsets (elements), swizzled; rows read have row&7 == l16&7.
    const int cg0 = ((0 + quad) ^ (l16 & 7)) * 8;   // k-half 0
    const int cg1 = ((4 + quad) ^ (l16 & 7)) * 8;   // k-half 1

    #define STAGE(buf, k0) {                                        \
        unsigned short* la = &smem[buf][tid * 8];                   \
        unsigned short* lb = &smem[2 + (buf)][tid * 8];             \
        const unsigned short* pa = gA + (k0);                       \
        const unsigned short* pb = gB + (k0);                       \
        async_cp16(pa,            la);                              \
        async_cp16(pa + 32 * DIM, la + 2048);                       \
        async_cp16(pa + 64 * DIM, la + 4096);                       \
        async_cp16(pa + 96 * DIM, la + 6144);                       \
        async_cp16(pb,            lb);                              \
        async_cp16(pb + 32 * DIM, lb + 2048);                       \
        async_cp16(pb + 64 * DIM, lb + 4096);                       \
        async_cp16(pb + 96 * DIM, lb + 6144);                       \
    }

    STAGE(0, 0)
    __syncthreads();   // drain prologue stage

    for (int k = 0; k < DIM / 64; ++k) {
        if (k < DIM / 64 - 1) STAGE((k + 1) & 1, (k + 1) * 64)   // prefetch next
        const unsigned short* Ab = smem[k & 1];
        const unsigned short* Bb = smem[2 + (k & 1)];
        #pragma unroll
        for (int h = 0; h < 2; ++h) {
            const int cg = h ? cg1 : cg0;
            bf16x8 af[4], bf[4];
            #pragma unroll
            for (int t = 0; t < 4; ++t) {
                af[t] = *reinterpret_cast<const bf16x8*>(
                    Ab + (wr * 64 + t * 16 + l16) * 64 + cg);
                bf[t] = *reinterpret_cast<const bf16x8*>(
                    Bb + (wc * 64 + t * 16 + l16) * 64 + cg);
            }
            #pragma unroll
            for (int i = 0; i < 4; ++i)
                #pragma unroll
                for (int j = 0; j < 4; ++j)
                    acc[i][j] = __builtin_amdgcn_mfma_f32_16x16x32_bf16(
                        af[i], bf[j], acc[i][j], 0, 0, 0);
        }
        __syncthreads();   // drains vmcnt(0): prefetched tile complete, reads done
    }
    // After the final barrier every wave is done with the bf16 tiles ->
    // smem is reusable as per-wave transpose scratch (wave-private regions,
    // no further barriers needed).
    float* tbuf = reinterpret_cast<float*>(&smem[0][0]) + wave * 4096; // 64x64 f32

    // Main epilogue. C/D layout: col = lane&15, row = quad*4 + reg.
    // Also deposit the finished value into the transpose buffer at [c][r^(c&31)]
    // (XOR swizzle keeps both the write and the transposed read <=2-way).
    const int row0 = bRow + wr * 64;
    const int col0 = bCol + wc * 64;
    {
        float snc[4];
        #pragma unroll
        for (int j = 0; j < 4; ++j) snc[j] = sn[col0 + j * 16 + l16];

        #pragma unroll
        for (int i = 0; i < 4; ++i) {
            #pragma unroll
            for (int rr = 0; rr < 4; ++rr) {
                const int rloc = i * 16 + quad * 4 + rr;
                const int row  = row0 + rloc;
                const float snr = sn[row];
                float* orow = out + (size_t)row * N_ROWS;
                #pragma unroll
                for (int j = 0; j < 4; ++j) {
                    const int cloc = j * 16 + l16;
                    const int col  = col0 + cloc;
                    float v = snr + snc[j] - 2.0f * acc[i][j][rr];
                    float o = (row == col) ? 0.0f : -sqrtf(fmaxf(v, 0.0f));
                    orow[col] = o;
                    tbuf[cloc * 64 + (rloc ^ (cloc & 31))] = o;
                }
            }
        }
    }

    // Mirror tile (bj,bi) = transpose of this wave's 64x64 quadrant, read back
    // from the wave-private LDS buffer in coalesced-store order.
    if (!diag) {
        #pragma unroll
        for (int p = 0; p < 4; ++p) {
            #pragma unroll
            for (int rr = 0; rr < 4; ++rr) {
                const int rT  = p * 16 + quad * 4 + rr;   // mirror-local row = orig col
                const int row = bCol + wc * 64 + rT;
                float* orow = out + (size_t)row * N_ROWS;
                #pragma unroll
                for (int q = 0; q < 4; ++q) {
                    const int cT = q * 16 + l16;          // mirror-local col = orig row
                    orow[bRow + wr * 64 + cT] =
                        tbuf[rT * 64 + (cT ^ (rT & 31))];
                }
            }
        }
    }
}

extern "C" void kernel_launch(void* const* d_in, const int* in_sizes, int n_in,
                              void* d_out, int out_size, void* d_ws, size_t ws_size,
                              hipStream_t stream) {
    const float* F = (const float*)d_in[0];
    float* out = (float*)d_out;

    unsigned short* Fb = (unsigned short*)d_ws;                       // 8 MiB bf16 copy
    float* sn = (float*)((char*)d_ws + (size_t)N_ROWS * DIM * 2);     // 32 KiB norms

    fs_norm_convert<<<N_ROWS / 4, 256, 0, stream>>>(F, Fb, sn);

    fs_gemm_sym<<<dim3(NBLK), 256, 0, stream>>>(Fb, sn, out);
}